// Round 2
// baseline (745.918 us; speedup 1.0000x reference)
//
#include <hip/hip_runtime.h>
#include <hip/hip_bf16.h>
#include <float.h>

#define N_NODES 30000
#define IN_CH   256
#define HID     128
#define HEADS   4
#define OUT_CH  256
#define N_EDGES 480000
#define TOT_E   (N_EDGES + N_NODES)

typedef unsigned short u16;   // bf16 bits

__device__ inline float bf2f(u16 u) {
    union { unsigned int i; float f; } v; v.i = ((unsigned int)u) << 16; return v.f;
}
__device__ inline u16 f2bf(float f) {
    union { float f; unsigned int i; } u; u.f = f;
    unsigned int r = u.i + 0x7FFF + ((u.i >> 16) & 1);
    return (u16)(r >> 16);
}

__device__ inline void load4(const float* p, float* o) {
    float4 v = *(const float4*)p; o[0]=v.x; o[1]=v.y; o[2]=v.z; o[3]=v.w;
}
__device__ inline void store4f(float* p, float a, float b, float c, float d) {
    *(float4*)p = make_float4(a,b,c,d);
}
__device__ inline void store4b(u16* p, float a, float b, float c, float d) {
    ushort4 o; o.x=f2bf(a); o.y=f2bf(b); o.z=f2bf(c); o.w=f2bf(d);
    *(ushort4*)p = o;
}

// ---------- dtype detection: bf16 exponent field vs fp32 mantissa bits -----
__global__ void detect_k(const unsigned int* __restrict__ w, int* __restrict__ flag) {
    __shared__ int votes;
    if (threadIdx.x == 0) votes = 0;
    __syncthreads();
    int v = 0;
    for (int i = threadIdx.x; i < 2048; i += 256) {
        unsigned int e = (w[i] >> 7) & 0xFFu;
        if (e >= 100u && e <= 140u) v++;
    }
    atomicAdd(&votes, v);
    __syncthreads();
    if (threadIdx.x == 0) *flag = (votes > 1024) ? 1 : 0;
}

// materialize an input as fp32 regardless of its on-disk dtype
__global__ void convert_k(const void* __restrict__ in, float* __restrict__ out,
                          int n, const int* __restrict__ flag) {
    int i = blockIdx.x * blockDim.x + threadIdx.x;
    if (i >= n) return;
    if (*flag) out[i] = bf2f(((const u16*)in)[i]);
    else       out[i] = ((const float*)in)[i];
}

// ---------------- GEMM: C[M,N] = A[M,K] @ B[K,N], fp32 --------------------
// 128x128 tile, 256 threads, 8x8 per thread, BK=16, reg-double-buffered.
__global__ __launch_bounds__(256) void gemm_k(const float* __restrict__ A,
                                              const float* __restrict__ B,
                                              float* __restrict__ C,
                                              int M, int N, int K)
{
    __shared__ float As[16][132];
    __shared__ float Bs[16][132];

    const int tid = threadIdx.x;
    const int tx = tid & 15;
    const int ty = tid >> 4;
    const int row0 = blockIdx.y * 128;
    const int col0 = blockIdx.x * 128;

    const int sa_r = tid >> 2;
    const int sa_k = (tid & 3) << 2;
    const int sb_r = tid >> 4;
    const int sb_c = (tid & 15) << 2;

    float av0[4], av1[4];
    float4 bv0, bv1;

    #define LOAD_TILE(K0)                                                      \
        do {                                                                   \
            int ar0 = row0 + sa_r, ar1 = ar0 + 64;                             \
            av0[0]=av0[1]=av0[2]=av0[3]=0.f;                                   \
            av1[0]=av1[1]=av1[2]=av1[3]=0.f;                                   \
            if (ar0 < M) load4(A + (size_t)ar0 * K + (K0) + sa_k, av0);        \
            if (ar1 < M) load4(A + (size_t)ar1 * K + (K0) + sa_k, av1);        \
            bv0 = *(const float4*)(B + (size_t)((K0) + sb_r) * N + col0 + sb_c);      \
            bv1 = *(const float4*)(B + (size_t)((K0) + sb_r) * N + col0 + sb_c + 64); \
        } while (0)

    float acc[8][8] = {};
    LOAD_TILE(0);

    for (int k0 = 0; k0 < K; k0 += 16) {
        __syncthreads();
        #pragma unroll
        for (int i = 0; i < 4; ++i) {
            As[sa_k + i][sa_r]      = av0[i];
            As[sa_k + i][sa_r + 64] = av1[i];
        }
        *(float4*)&Bs[sb_r][sb_c]      = bv0;
        *(float4*)&Bs[sb_r][sb_c + 64] = bv1;
        __syncthreads();

        if (k0 + 16 < K) LOAD_TILE(k0 + 16);

        #pragma unroll
        for (int k = 0; k < 16; ++k) {
            float4 a0 = *(const float4*)&As[k][ty << 2];
            float4 a1 = *(const float4*)&As[k][64 + (ty << 2)];
            float4 b0 = *(const float4*)&Bs[k][tx << 2];
            float4 b1 = *(const float4*)&Bs[k][64 + (tx << 2)];
            float a[8] = {a0.x,a0.y,a0.z,a0.w, a1.x,a1.y,a1.z,a1.w};
            float b[8] = {b0.x,b0.y,b0.z,b0.w, b1.x,b1.y,b1.z,b1.w};
            #pragma unroll
            for (int i = 0; i < 8; ++i)
                #pragma unroll
                for (int j = 0; j < 8; ++j)
                    acc[i][j] += a[i] * b[j];
        }
    }
    #undef LOAD_TILE

    #pragma unroll
    for (int i = 0; i < 8; ++i) {
        int r = row0 + ((i >> 2) << 6) + (ty << 2) + (i & 3);
        if (r < M) {
            float* Cr = C + (size_t)r * N + col0;
            *(float4*)(Cr + (tx << 2)) =
                make_float4(acc[i][0], acc[i][1], acc[i][2], acc[i][3]);
            *(float4*)(Cr + 64 + (tx << 2)) =
                make_float4(acc[i][4], acc[i][5], acc[i][6], acc[i][7]);
        }
    }
}

// ------------- per-node attention logits ------------------------------------
__global__ void logits_k(const float* __restrict__ h,
                         const float* __restrict__ a_s,
                         const float* __restrict__ a_d,
                         float* __restrict__ als, float* __restrict__ ald,
                         int H, int C)
{
    int n = blockIdx.x;
    int head = threadIdx.x >> 6;
    int lane = threadIdx.x & 63;
    const float* row = h + (size_t)n * H * C + head * C;
    float ss = 0.f, sd = 0.f;
    for (int c = lane; c < C; c += 64) {
        float v = row[c];
        ss += v * a_s[head*C + c];
        sd += v * a_d[head*C + c];
    }
    for (int o = 32; o > 0; o >>= 1) { ss += __shfl_down(ss,o); sd += __shfl_down(sd,o); }
    if (lane == 0) { als[(size_t)n*H + head] = ss; ald[(size_t)n*H + head] = sd; }
}

// ---------------- CSR build -------------------------------------------------
__global__ void zero_k(int* p, int n) {
    int i = blockIdx.x*blockDim.x + threadIdx.x; if (i < n) p[i] = 0;
}
__global__ void count_k(const int* __restrict__ ei, int* __restrict__ cnt) {
    int i = blockIdx.x*blockDim.x + threadIdx.x;
    if (i >= TOT_E) return;
    int d = (i < N_EDGES) ? ei[N_EDGES + i] : (i - N_EDGES);
    atomicAdd(&cnt[d], 1);
}
__global__ __launch_bounds__(1024) void scan_k(const int* __restrict__ cnt,
                                               int* __restrict__ offs,
                                               int* __restrict__ cursor)
{
    __shared__ int sm[1024];
    __shared__ int carry_s;
    if (threadIdx.x == 0) carry_s = 0;
    __syncthreads();
    for (int base = 0; base < N_NODES; base += 1024) {
        int i = base + threadIdx.x;
        int v = (i < N_NODES) ? cnt[i] : 0;
        sm[threadIdx.x] = v;
        __syncthreads();
        for (int off = 1; off < 1024; off <<= 1) {
            int t = (threadIdx.x >= off) ? sm[threadIdx.x - off] : 0;
            __syncthreads();
            sm[threadIdx.x] += t;
            __syncthreads();
        }
        int c = carry_s;
        if (i < N_NODES) {
            offs[i+1]  = c + sm[threadIdx.x];
            cursor[i]  = c + sm[threadIdx.x] - v;
        }
        __syncthreads();
        if (threadIdx.x == 1023) carry_s = c + sm[1023];
        __syncthreads();
    }
    if (threadIdx.x == 0) offs[0] = 0;
}
__global__ void scatter_k(const int* __restrict__ ei, int* __restrict__ cursor,
                          int* __restrict__ ssrc)
{
    int i = blockIdx.x*blockDim.x + threadIdx.x;
    if (i >= TOT_E) return;
    int s, d;
    if (i < N_EDGES) { s = ei[i]; d = ei[N_EDGES + i]; }
    else             { s = i - N_EDGES; d = s; }
    int pos = atomicAdd(&cursor[d], 1);
    ssrc[pos] = s;
}

// ---------------- per-dst softmax + weighted aggregation --------------------
// one block per dst node; T = H*C/4 threads, each owns 4 contiguous channels.
// v2: wave-shuffle reductions for max/sum; pass 3 stages (src, weight) per
// chunk into LDS, then gathers h rows with 4 independent loads in flight
// (breaks the ssrc->als->h dependent-load chain that made v1 latency-bound).
template<int H, int C, bool PRELU, bool DUAL>
__global__ void aggregate_k(const float* __restrict__ h,
                            const float* __restrict__ als,
                            const float* __restrict__ ald,
                            const int* __restrict__ offs,
                            const int* __restrict__ ssrc,
                            const float* __restrict__ bias,
                            const float* __restrict__ prelu_w,
                            void* __restrict__ outv,
                            const int* __restrict__ flag)
{
    constexpr int CT = H * C;
    constexpr int T  = CT / 4;
    constexpr int NW = T / 64;            // waves per block
    int n   = blockIdx.x;
    int tid = threadIdx.x;
    int beg = offs[n], end = offs[n+1];

    __shared__ float s_ald[H], s_m[H], s_inv[H];
    __shared__ float red[H][NW];
    __shared__ int   sh_s[T];
    __shared__ float sh_w[H][T];

    if (tid < H) s_ald[tid] = ald[(size_t)n*H + tid];
    __syncthreads();

    // sweep 1: per-head max of leaky logits (wave shuffle reduce)
    float lmax[H];
#pragma unroll
    for (int hh = 0; hh < H; ++hh) lmax[hh] = -FLT_MAX;
    for (int e = beg + tid; e < end; e += T) {
        int s = ssrc[e];
#pragma unroll
        for (int hh = 0; hh < H; ++hh) {
            float l = als[(size_t)s*H + hh] + s_ald[hh];
            l = (l >= 0.f) ? l : 0.2f*l;
            lmax[hh] = fmaxf(lmax[hh], l);
        }
    }
#pragma unroll
    for (int hh = 0; hh < H; ++hh) {
        float v = lmax[hh];
#pragma unroll
        for (int o = 32; o > 0; o >>= 1) v = fmaxf(v, __shfl_xor(v, o));
        if ((tid & 63) == 0) red[hh][tid >> 6] = v;
    }
    __syncthreads();
    if (tid < H) {
        float v = red[tid][0];
#pragma unroll
        for (int w2 = 1; w2 < NW; ++w2) v = fmaxf(v, red[tid][w2]);
        s_m[tid] = v;
    }
    __syncthreads();

    // sweep 2: per-head sum of exp(l - m) (wave shuffle reduce)
    float lsum[H];
#pragma unroll
    for (int hh = 0; hh < H; ++hh) lsum[hh] = 0.f;
    for (int e = beg + tid; e < end; e += T) {
        int s = ssrc[e];
#pragma unroll
        for (int hh = 0; hh < H; ++hh) {
            float l = als[(size_t)s*H + hh] + s_ald[hh];
            l = (l >= 0.f) ? l : 0.2f*l;
            lsum[hh] += __expf(l - s_m[hh]);
        }
    }
#pragma unroll
    for (int hh = 0; hh < H; ++hh) {
        float v = lsum[hh];
#pragma unroll
        for (int o = 32; o > 0; o >>= 1) v += __shfl_xor(v, o);
        if ((tid & 63) == 0) red[hh][tid >> 6] = v;
    }
    __syncthreads();
    if (tid < H) {
        float v = 0.f;
#pragma unroll
        for (int w2 = 0; w2 < NW; ++w2) v += red[tid][w2];
        s_inv[tid] = 1.0f / v;
    }
    __syncthreads();

    // pass 3: chunk-staged weighted gather
    const int hh = (4*tid) / C;
    float ax = 0.f, ay = 0.f, az = 0.f, aw = 0.f;
    for (int chunk = beg; chunk < end; chunk += T) {
        int e = chunk + tid;
        if (e < end) {
            int s = ssrc[e];
            sh_s[tid] = s;
#pragma unroll
            for (int h2 = 0; h2 < H; ++h2) {
                float l = als[(size_t)s*H + h2] + s_ald[h2];
                l = (l >= 0.f) ? l : 0.2f*l;
                sh_w[h2][tid] = __expf(l - s_m[h2]) * s_inv[h2];
            }
        }
        __syncthreads();
        int cnt = min(T, end - chunk);
        int j = 0;
        for (; j + 4 <= cnt; j += 4) {
            int s0 = sh_s[j+0], s1 = sh_s[j+1], s2 = sh_s[j+2], s3 = sh_s[j+3];
            float w0 = sh_w[hh][j+0], w1 = sh_w[hh][j+1];
            float w2 = sh_w[hh][j+2], w3 = sh_w[hh][j+3];
            float4 v0 = *(const float4*)(h + (size_t)s0*CT + 4*tid);
            float4 v1 = *(const float4*)(h + (size_t)s1*CT + 4*tid);
            float4 v2 = *(const float4*)(h + (size_t)s2*CT + 4*tid);
            float4 v3 = *(const float4*)(h + (size_t)s3*CT + 4*tid);
            ax += w0*v0.x; ay += w0*v0.y; az += w0*v0.z; aw += w0*v0.w;
            ax += w1*v1.x; ay += w1*v1.y; az += w1*v1.z; aw += w1*v1.w;
            ax += w2*v2.x; ay += w2*v2.y; az += w2*v2.z; aw += w2*v2.w;
            ax += w3*v3.x; ay += w3*v3.y; az += w3*v3.z; aw += w3*v3.w;
        }
        for (; j < cnt; ++j) {
            int s0 = sh_s[j];
            float w0 = sh_w[hh][j];
            float4 v0 = *(const float4*)(h + (size_t)s0*CT + 4*tid);
            ax += w0*v0.x; ay += w0*v0.y; az += w0*v0.z; aw += w0*v0.w;
        }
        __syncthreads();
    }

    float bb[4];
    load4(bias + 4*tid, bb);
    ax += bb[0]; ay += bb[1]; az += bb[2]; aw += bb[3];
    if (PRELU) {
        float pw = *prelu_w;
        ax = ax >= 0.f ? ax : pw*ax;
        ay = ay >= 0.f ? ay : pw*ay;
        az = az >= 0.f ? az : pw*az;
        aw = aw >= 0.f ? aw : pw*aw;
    }
    size_t ofs = (size_t)n*CT + 4*tid;
    if (DUAL) {
        if (*flag) store4b((u16*)outv + ofs, ax, ay, az, aw);
        else       store4f((float*)outv + ofs, ax, ay, az, aw);
    } else {
        store4f((float*)outv + ofs, ax, ay, az, aw);
    }
}

// ---------------------------------------------------------------------------
extern "C" void kernel_launch(void* const* d_in, const int* in_sizes, int n_in,
                              void* d_out, int out_size, void* d_ws, size_t ws_size,
                              hipStream_t stream)
{
    const void* x   = d_in[0];
    const int*  ei  = (const int*)d_in[1];
    const void* W1  = d_in[2];
    const void* as1 = d_in[3];
    const void* ad1 = d_in[4];
    const void* b1  = d_in[5];
    const void* pw  = d_in[6];
    const void* W2  = d_in[7];
    const void* as2 = d_in[8];
    const void* ad2 = d_in[9];
    const void* b2  = d_in[10];

    float* ws = (float*)d_ws;
    int*   flag = (int*)ws;                               // +4 pad
    float* xf   = ws + 4;                                 // 7,680,000
    float* W1f  = xf  + (size_t)N_NODES*IN_CH;            // 131,072
    float* W2f  = W1f + IN_CH*HEADS*HID;                  // 131,072
    float* as1f = W2f + HEADS*HID*OUT_CH;                 // 512
    float* ad1f = as1f + HEADS*HID;                       // 512
    float* b1f  = ad1f + HEADS*HID;                       // 512
    float* as2f = b1f  + HEADS*HID;                       // 256
    float* ad2f = as2f + OUT_CH;                          // 256
    float* b2f  = ad2f + OUT_CH;                          // 256
    float* pwf  = b2f  + OUT_CH;                          // 4 (pad)
    float* h1   = pwf + 4;                                // 15,360,000
    float* h1p  = h1  + (size_t)N_NODES*512;              // 15,360,000
    float* als1 = h1p + (size_t)N_NODES*512;              // 120,000
    float* ald1 = als1 + (size_t)N_NODES*4;               // 120,000
    float* als2v = ald1 + (size_t)N_NODES*4;              // 30,000
    float* ald2v = als2v + N_NODES;                       // 30,000
    int*   cnt    = (int*)(ald2v + N_NODES);              // 30,000
    int*   offs   = cnt + N_NODES;                        // 30,001
    int*   cursor = offs + (N_NODES+1);                   // 30,000
    int*   ssrc   = cursor + N_NODES;                     // 510,000
    float* h2 = h1;  // h1 dead after aggregate1; reuse for h2 (30000*256)

    // dtype detect + materialize fp32 inputs
    detect_k<<<1, 256, 0, stream>>>((const unsigned int*)x, flag);
    convert_k<<<(N_NODES*IN_CH+255)/256, 256, 0, stream>>>(x,  xf,  N_NODES*IN_CH, flag);
    convert_k<<<(IN_CH*HEADS*HID+255)/256, 256, 0, stream>>>(W1, W1f, IN_CH*HEADS*HID, flag);
    convert_k<<<(HEADS*HID*OUT_CH+255)/256, 256, 0, stream>>>(W2, W2f, HEADS*HID*OUT_CH, flag);
    convert_k<<<2, 256, 0, stream>>>(as1, as1f, HEADS*HID, flag);
    convert_k<<<2, 256, 0, stream>>>(ad1, ad1f, HEADS*HID, flag);
    convert_k<<<2, 256, 0, stream>>>(b1,  b1f,  HEADS*HID, flag);
    convert_k<<<1, 256, 0, stream>>>(as2, as2f, OUT_CH, flag);
    convert_k<<<1, 256, 0, stream>>>(ad2, ad2f, OUT_CH, flag);
    convert_k<<<1, 256, 0, stream>>>(b2,  b2f,  OUT_CH, flag);
    convert_k<<<1, 64,  0, stream>>>(pw,  pwf,  1, flag);

    // CSR build
    zero_k   <<<(N_NODES+255)/256, 256, 0, stream>>>(cnt, N_NODES);
    count_k  <<<(TOT_E+255)/256,   256, 0, stream>>>(ei, cnt);
    scan_k   <<<1, 1024, 0, stream>>>(cnt, offs, cursor);
    scatter_k<<<(TOT_E+255)/256,   256, 0, stream>>>(ei, cursor, ssrc);

    // ---- layer 1 ----
    dim3 g1(512/128, (N_NODES+127)/128);
    gemm_k<<<g1, 256, 0, stream>>>(xf, W1f, h1, N_NODES, 512, IN_CH);
    logits_k<<<N_NODES, 256, 0, stream>>>(h1, as1f, ad1f, als1, ald1, HEADS, HID);
    aggregate_k<HEADS, HID, true, false>
        <<<N_NODES, (HEADS*HID)/4, 0, stream>>>(h1, als1, ald1, offs, ssrc, b1f, pwf, h1p, flag);

    // ---- layer 2 ----
    dim3 g2(256/128, (N_NODES+127)/128);
    gemm_k<<<g2, 256, 0, stream>>>(h1p, W2f, h2, N_NODES, OUT_CH, 512);
    logits_k<<<N_NODES, 64, 0, stream>>>(h2, as2f, ad2f, als2v, ald2v, 1, OUT_CH);
    aggregate_k<1, OUT_CH, false, true>
        <<<N_NODES, OUT_CH/4, 0, stream>>>(h2, als2v, ald2v, offs, ssrc, b2f, nullptr, d_out, flag);
}

// Round 3
// 668.091 us; speedup vs baseline: 1.1165x; 1.1165x over previous
//
#include <hip/hip_runtime.h>
#include <hip/hip_bf16.h>
#include <float.h>

#define N_NODES 30000
#define IN_CH   256
#define HID     128
#define HEADS   4
#define OUT_CH  256
#define N_EDGES 480000
#define TOT_E   (N_EDGES + N_NODES)

typedef unsigned short u16;   // bf16 bits

__device__ inline float bf2f(u16 u) {
    union { unsigned int i; float f; } v; v.i = ((unsigned int)u) << 16; return v.f;
}
__device__ inline u16 f2bf(float f) {
    union { float f; unsigned int i; } u; u.f = f;
    unsigned int r = u.i + 0x7FFF + ((u.i >> 16) & 1);
    return (u16)(r >> 16);
}

__device__ inline void load4(const float* p, float* o) {
    float4 v = *(const float4*)p; o[0]=v.x; o[1]=v.y; o[2]=v.z; o[3]=v.w;
}
__device__ inline void store4f(float* p, float a, float b, float c, float d) {
    *(float4*)p = make_float4(a,b,c,d);
}
__device__ inline void store4b(u16* p, float a, float b, float c, float d) {
    ushort4 o; o.x=f2bf(a); o.y=f2bf(b); o.z=f2bf(c); o.w=f2bf(d);
    *(ushort4*)p = o;
}

// ---------- dtype detection: bf16 exponent field vs fp32 mantissa bits -----
__global__ void detect_k(const unsigned int* __restrict__ w, int* __restrict__ flag) {
    __shared__ int votes;
    if (threadIdx.x == 0) votes = 0;
    __syncthreads();
    int v = 0;
    for (int i = threadIdx.x; i < 2048; i += 256) {
        unsigned int e = (w[i] >> 7) & 0xFFu;
        if (e >= 100u && e <= 140u) v++;
    }
    atomicAdd(&votes, v);
    __syncthreads();
    if (threadIdx.x == 0) *flag = (votes > 1024) ? 1 : 0;
}

// materialize an input as fp32 regardless of its on-disk dtype
__global__ void convert_k(const void* __restrict__ in, float* __restrict__ out,
                          int n, const int* __restrict__ flag) {
    int i = blockIdx.x * blockDim.x + threadIdx.x;
    if (i >= n) return;
    if (*flag) out[i] = bf2f(((const u16*)in)[i]);
    else       out[i] = ((const float*)in)[i];
}

// fp32 -> bf16 mirror copy (for the gather tables)
__global__ void f2bf_k(const float* __restrict__ in, u16* __restrict__ out, int n) {
    int idx = (blockIdx.x * blockDim.x + threadIdx.x) * 4;
    if (idx >= n) return;
    float4 v = *(const float4*)(in + idx);
    ushort4 o; o.x=f2bf(v.x); o.y=f2bf(v.y); o.z=f2bf(v.z); o.w=f2bf(v.w);
    *(ushort4*)(out + idx) = o;
}

// ---------------- GEMM: C[M,N] = A[M,K] @ B[K,N], fp32 --------------------
// 128x128 tile, 256 threads, 8x8 per thread, BK=16, reg-double-buffered.
__global__ __launch_bounds__(256) void gemm_k(const float* __restrict__ A,
                                              const float* __restrict__ B,
                                              float* __restrict__ C,
                                              int M, int N, int K)
{
    __shared__ float As[16][132];
    __shared__ float Bs[16][132];

    const int tid = threadIdx.x;
    const int tx = tid & 15;
    const int ty = tid >> 4;
    const int row0 = blockIdx.y * 128;
    const int col0 = blockIdx.x * 128;

    const int sa_r = tid >> 2;
    const int sa_k = (tid & 3) << 2;
    const int sb_r = tid >> 4;
    const int sb_c = (tid & 15) << 2;

    float av0[4], av1[4];
    float4 bv0, bv1;

    #define LOAD_TILE(K0)                                                      \
        do {                                                                   \
            int ar0 = row0 + sa_r, ar1 = ar0 + 64;                             \
            av0[0]=av0[1]=av0[2]=av0[3]=0.f;                                   \
            av1[0]=av1[1]=av1[2]=av1[3]=0.f;                                   \
            if (ar0 < M) load4(A + (size_t)ar0 * K + (K0) + sa_k, av0);        \
            if (ar1 < M) load4(A + (size_t)ar1 * K + (K0) + sa_k, av1);        \
            bv0 = *(const float4*)(B + (size_t)((K0) + sb_r) * N + col0 + sb_c);      \
            bv1 = *(const float4*)(B + (size_t)((K0) + sb_r) * N + col0 + sb_c + 64); \
        } while (0)

    float acc[8][8] = {};
    LOAD_TILE(0);

    for (int k0 = 0; k0 < K; k0 += 16) {
        __syncthreads();
        #pragma unroll
        for (int i = 0; i < 4; ++i) {
            As[sa_k + i][sa_r]      = av0[i];
            As[sa_k + i][sa_r + 64] = av1[i];
        }
        *(float4*)&Bs[sb_r][sb_c]      = bv0;
        *(float4*)&Bs[sb_r][sb_c + 64] = bv1;
        __syncthreads();

        if (k0 + 16 < K) LOAD_TILE(k0 + 16);

        #pragma unroll
        for (int k = 0; k < 16; ++k) {
            float4 a0 = *(const float4*)&As[k][ty << 2];
            float4 a1 = *(const float4*)&As[k][64 + (ty << 2)];
            float4 b0 = *(const float4*)&Bs[k][tx << 2];
            float4 b1 = *(const float4*)&Bs[k][64 + (tx << 2)];
            float a[8] = {a0.x,a0.y,a0.z,a0.w, a1.x,a1.y,a1.z,a1.w};
            float b[8] = {b0.x,b0.y,b0.z,b0.w, b1.x,b1.y,b1.z,b1.w};
            #pragma unroll
            for (int i = 0; i < 8; ++i)
                #pragma unroll
                for (int j = 0; j < 8; ++j)
                    acc[i][j] += a[i] * b[j];
        }
    }
    #undef LOAD_TILE

    #pragma unroll
    for (int i = 0; i < 8; ++i) {
        int r = row0 + ((i >> 2) << 6) + (ty << 2) + (i & 3);
        if (r < M) {
            float* Cr = C + (size_t)r * N + col0;
            *(float4*)(Cr + (tx << 2)) =
                make_float4(acc[i][0], acc[i][1], acc[i][2], acc[i][3]);
            *(float4*)(Cr + 64 + (tx << 2)) =
                make_float4(acc[i][4], acc[i][5], acc[i][6], acc[i][7]);
        }
    }
}

// ------------- per-node attention logits ------------------------------------
__global__ void logits_k(const float* __restrict__ h,
                         const float* __restrict__ a_s,
                         const float* __restrict__ a_d,
                         float* __restrict__ als, float* __restrict__ ald,
                         int H, int C)
{
    int n = blockIdx.x;
    int head = threadIdx.x >> 6;
    int lane = threadIdx.x & 63;
    const float* row = h + (size_t)n * H * C + head * C;
    float ss = 0.f, sd = 0.f;
    for (int c = lane; c < C; c += 64) {
        float v = row[c];
        ss += v * a_s[head*C + c];
        sd += v * a_d[head*C + c];
    }
    for (int o = 32; o > 0; o >>= 1) { ss += __shfl_down(ss,o); sd += __shfl_down(sd,o); }
    if (lane == 0) { als[(size_t)n*H + head] = ss; ald[(size_t)n*H + head] = sd; }
}

// ---------------- CSR build -------------------------------------------------
__global__ void zero_k(int* p, int n) {
    int i = blockIdx.x*blockDim.x + threadIdx.x; if (i < n) p[i] = 0;
}
__global__ void count_k(const int* __restrict__ ei, int* __restrict__ cnt) {
    int i = blockIdx.x*blockDim.x + threadIdx.x;
    if (i >= TOT_E) return;
    int d = (i < N_EDGES) ? ei[N_EDGES + i] : (i - N_EDGES);
    atomicAdd(&cnt[d], 1);
}
__global__ __launch_bounds__(1024) void scan_k(const int* __restrict__ cnt,
                                               int* __restrict__ offs,
                                               int* __restrict__ cursor)
{
    __shared__ int sm[1024];
    __shared__ int carry_s;
    if (threadIdx.x == 0) carry_s = 0;
    __syncthreads();
    for (int base = 0; base < N_NODES; base += 1024) {
        int i = base + threadIdx.x;
        int v = (i < N_NODES) ? cnt[i] : 0;
        sm[threadIdx.x] = v;
        __syncthreads();
        for (int off = 1; off < 1024; off <<= 1) {
            int t = (threadIdx.x >= off) ? sm[threadIdx.x - off] : 0;
            __syncthreads();
            sm[threadIdx.x] += t;
            __syncthreads();
        }
        int c = carry_s;
        if (i < N_NODES) {
            offs[i+1]  = c + sm[threadIdx.x];
            cursor[i]  = c + sm[threadIdx.x] - v;
        }
        __syncthreads();
        if (threadIdx.x == 1023) carry_s = c + sm[1023];
        __syncthreads();
    }
    if (threadIdx.x == 0) offs[0] = 0;
}
__global__ void scatter_k(const int* __restrict__ ei, int* __restrict__ cursor,
                          int* __restrict__ ssrc)
{
    int i = blockIdx.x*blockDim.x + threadIdx.x;
    if (i >= TOT_E) return;
    int s, d;
    if (i < N_EDGES) { s = ei[i]; d = ei[N_EDGES + i]; }
    else             { s = i - N_EDGES; d = s; }
    int pos = atomicAdd(&cursor[d], 1);
    ssrc[pos] = s;
}

// ---------------- per-dst softmax + weighted aggregation --------------------
// one block per dst node; T = H*C/4 threads, each owns 4 contiguous channels.
// v3: message gather reads a bf16 mirror (hb) of h -> halves the gather
// traffic that round-2 counters showed saturating the L2-miss path at
// ~3.7 TB/s. Logits/softmax/accumulation remain fp32.
template<int H, int C, bool PRELU, bool DUAL>
__global__ void aggregate_k(const u16* __restrict__ hb,
                            const float* __restrict__ als,
                            const float* __restrict__ ald,
                            const int* __restrict__ offs,
                            const int* __restrict__ ssrc,
                            const float* __restrict__ bias,
                            const float* __restrict__ prelu_w,
                            void* __restrict__ outv,
                            const int* __restrict__ flag)
{
    constexpr int CT = H * C;
    constexpr int T  = CT / 4;
    constexpr int NW = T / 64;            // waves per block
    int n   = blockIdx.x;
    int tid = threadIdx.x;
    int beg = offs[n], end = offs[n+1];

    __shared__ float s_ald[H], s_m[H], s_inv[H];
    __shared__ float red[H][NW];
    __shared__ int   sh_s[T];
    __shared__ float sh_w[H][T];

    if (tid < H) s_ald[tid] = ald[(size_t)n*H + tid];
    __syncthreads();

    // sweep 1: per-head max of leaky logits (wave shuffle reduce)
    float lmax[H];
#pragma unroll
    for (int hh = 0; hh < H; ++hh) lmax[hh] = -FLT_MAX;
    for (int e = beg + tid; e < end; e += T) {
        int s = ssrc[e];
#pragma unroll
        for (int hh = 0; hh < H; ++hh) {
            float l = als[(size_t)s*H + hh] + s_ald[hh];
            l = (l >= 0.f) ? l : 0.2f*l;
            lmax[hh] = fmaxf(lmax[hh], l);
        }
    }
#pragma unroll
    for (int hh = 0; hh < H; ++hh) {
        float v = lmax[hh];
#pragma unroll
        for (int o = 32; o > 0; o >>= 1) v = fmaxf(v, __shfl_xor(v, o));
        if ((tid & 63) == 0) red[hh][tid >> 6] = v;
    }
    __syncthreads();
    if (tid < H) {
        float v = red[tid][0];
#pragma unroll
        for (int w2 = 1; w2 < NW; ++w2) v = fmaxf(v, red[tid][w2]);
        s_m[tid] = v;
    }
    __syncthreads();

    // sweep 2: per-head sum of exp(l - m) (wave shuffle reduce)
    float lsum[H];
#pragma unroll
    for (int hh = 0; hh < H; ++hh) lsum[hh] = 0.f;
    for (int e = beg + tid; e < end; e += T) {
        int s = ssrc[e];
#pragma unroll
        for (int hh = 0; hh < H; ++hh) {
            float l = als[(size_t)s*H + hh] + s_ald[hh];
            l = (l >= 0.f) ? l : 0.2f*l;
            lsum[hh] += __expf(l - s_m[hh]);
        }
    }
#pragma unroll
    for (int hh = 0; hh < H; ++hh) {
        float v = lsum[hh];
#pragma unroll
        for (int o = 32; o > 0; o >>= 1) v += __shfl_xor(v, o);
        if ((tid & 63) == 0) red[hh][tid >> 6] = v;
    }
    __syncthreads();
    if (tid < H) {
        float v = 0.f;
#pragma unroll
        for (int w2 = 0; w2 < NW; ++w2) v += red[tid][w2];
        s_inv[tid] = 1.0f / v;
    }
    __syncthreads();

    // pass 3: chunk-staged weighted gather from the bf16 mirror
    const int hh = (4*tid) / C;
    float ax = 0.f, ay = 0.f, az = 0.f, aw = 0.f;
    for (int chunk = beg; chunk < end; chunk += T) {
        int e = chunk + tid;
        if (e < end) {
            int s = ssrc[e];
            sh_s[tid] = s;
#pragma unroll
            for (int h2 = 0; h2 < H; ++h2) {
                float l = als[(size_t)s*H + h2] + s_ald[h2];
                l = (l >= 0.f) ? l : 0.2f*l;
                sh_w[h2][tid] = __expf(l - s_m[h2]) * s_inv[h2];
            }
        }
        __syncthreads();
        int cnt = min(T, end - chunk);
        int j = 0;
        for (; j + 4 <= cnt; j += 4) {
            int s0 = sh_s[j+0], s1 = sh_s[j+1], s2 = sh_s[j+2], s3 = sh_s[j+3];
            float w0 = sh_w[hh][j+0], w1 = sh_w[hh][j+1];
            float w2 = sh_w[hh][j+2], w3 = sh_w[hh][j+3];
            ushort4 v0 = *(const ushort4*)(hb + (size_t)s0*CT + 4*tid);
            ushort4 v1 = *(const ushort4*)(hb + (size_t)s1*CT + 4*tid);
            ushort4 v2 = *(const ushort4*)(hb + (size_t)s2*CT + 4*tid);
            ushort4 v3 = *(const ushort4*)(hb + (size_t)s3*CT + 4*tid);
            ax += w0*bf2f(v0.x); ay += w0*bf2f(v0.y); az += w0*bf2f(v0.z); aw += w0*bf2f(v0.w);
            ax += w1*bf2f(v1.x); ay += w1*bf2f(v1.y); az += w1*bf2f(v1.z); aw += w1*bf2f(v1.w);
            ax += w2*bf2f(v2.x); ay += w2*bf2f(v2.y); az += w2*bf2f(v2.z); aw += w2*bf2f(v2.w);
            ax += w3*bf2f(v3.x); ay += w3*bf2f(v3.y); az += w3*bf2f(v3.z); aw += w3*bf2f(v3.w);
        }
        for (; j < cnt; ++j) {
            int s0 = sh_s[j];
            float w0 = sh_w[hh][j];
            ushort4 v0 = *(const ushort4*)(hb + (size_t)s0*CT + 4*tid);
            ax += w0*bf2f(v0.x); ay += w0*bf2f(v0.y); az += w0*bf2f(v0.z); aw += w0*bf2f(v0.w);
        }
        __syncthreads();
    }

    float bb[4];
    load4(bias + 4*tid, bb);
    ax += bb[0]; ay += bb[1]; az += bb[2]; aw += bb[3];
    if (PRELU) {
        float pw = *prelu_w;
        ax = ax >= 0.f ? ax : pw*ax;
        ay = ay >= 0.f ? ay : pw*ay;
        az = az >= 0.f ? az : pw*az;
        aw = aw >= 0.f ? aw : pw*aw;
    }
    size_t ofs = (size_t)n*CT + 4*tid;
    if (DUAL) {
        if (*flag) store4b((u16*)outv + ofs, ax, ay, az, aw);
        else       store4f((float*)outv + ofs, ax, ay, az, aw);
    } else {
        store4f((float*)outv + ofs, ax, ay, az, aw);
    }
}

// ---------------------------------------------------------------------------
extern "C" void kernel_launch(void* const* d_in, const int* in_sizes, int n_in,
                              void* d_out, int out_size, void* d_ws, size_t ws_size,
                              hipStream_t stream)
{
    const void* x   = d_in[0];
    const int*  ei  = (const int*)d_in[1];
    const void* W1  = d_in[2];
    const void* as1 = d_in[3];
    const void* ad1 = d_in[4];
    const void* b1  = d_in[5];
    const void* pw  = d_in[6];
    const void* W2  = d_in[7];
    const void* as2 = d_in[8];
    const void* ad2 = d_in[9];
    const void* b2  = d_in[10];

    float* ws = (float*)d_ws;
    int*   flag = (int*)ws;                               // +4 pad
    float* xf   = ws + 4;                                 // 7,680,000 (30.72 MB)
    float* W1f  = xf  + (size_t)N_NODES*IN_CH;            // 131,072
    float* W2f  = W1f + IN_CH*HEADS*HID;                  // 131,072
    float* as1f = W2f + HEADS*HID*OUT_CH;                 // 512
    float* ad1f = as1f + HEADS*HID;                       // 512
    float* b1f  = ad1f + HEADS*HID;                       // 512
    float* as2f = b1f  + HEADS*HID;                       // 256
    float* ad2f = as2f + OUT_CH;                          // 256
    float* b2f  = ad2f + OUT_CH;                          // 256
    float* pwf  = b2f  + OUT_CH;                          // 4 (pad)
    float* h1   = pwf + 4;                                // 15,360,000
    float* h1p  = h1  + (size_t)N_NODES*512;              // 15,360,000
    float* als1 = h1p + (size_t)N_NODES*512;              // 120,000
    float* ald1 = als1 + (size_t)N_NODES*4;               // 120,000
    float* als2v = ald1 + (size_t)N_NODES*4;              // 30,000
    float* ald2v = als2v + N_NODES;                       // 30,000
    int*   cnt    = (int*)(ald2v + N_NODES);              // 30,000
    int*   offs   = cnt + N_NODES;                        // 30,001
    int*   cursor = offs + (N_NODES+1);                   // 30,000
    int*   ssrc   = cursor + N_NODES;                     // 510,000
    float* h2 = h1;  // h1 dead after f2bf/logits1; reuse for h2 (30000*256)
    // bf16 gather mirrors alias the xf region (xf dead after gemm1):
    // h1b needs 30000*512*2 B = 30.72 MB == sizeof(xf). h2b reuses it after
    // aggregate1 is done with h1b.
    u16* h1b = (u16*)xf;
    u16* h2b = (u16*)xf;

    // dtype detect + materialize fp32 inputs
    detect_k<<<1, 256, 0, stream>>>((const unsigned int*)x, flag);
    convert_k<<<(N_NODES*IN_CH+255)/256, 256, 0, stream>>>(x,  xf,  N_NODES*IN_CH, flag);
    convert_k<<<(IN_CH*HEADS*HID+255)/256, 256, 0, stream>>>(W1, W1f, IN_CH*HEADS*HID, flag);
    convert_k<<<(HEADS*HID*OUT_CH+255)/256, 256, 0, stream>>>(W2, W2f, HEADS*HID*OUT_CH, flag);
    convert_k<<<2, 256, 0, stream>>>(as1, as1f, HEADS*HID, flag);
    convert_k<<<2, 256, 0, stream>>>(ad1, ad1f, HEADS*HID, flag);
    convert_k<<<2, 256, 0, stream>>>(b1,  b1f,  HEADS*HID, flag);
    convert_k<<<1, 256, 0, stream>>>(as2, as2f, OUT_CH, flag);
    convert_k<<<1, 256, 0, stream>>>(ad2, ad2f, OUT_CH, flag);
    convert_k<<<1, 256, 0, stream>>>(b2,  b2f,  OUT_CH, flag);
    convert_k<<<1, 64,  0, stream>>>(pw,  pwf,  1, flag);

    // CSR build
    zero_k   <<<(N_NODES+255)/256, 256, 0, stream>>>(cnt, N_NODES);
    count_k  <<<(TOT_E+255)/256,   256, 0, stream>>>(ei, cnt);
    scan_k   <<<1, 1024, 0, stream>>>(cnt, offs, cursor);
    scatter_k<<<(TOT_E+255)/256,   256, 0, stream>>>(ei, cursor, ssrc);

    // ---- layer 1 ----
    dim3 g1(512/128, (N_NODES+127)/128);
    gemm_k<<<g1, 256, 0, stream>>>(xf, W1f, h1, N_NODES, 512, IN_CH);
    // xf dead from here; build bf16 mirror of h1 over it
    f2bf_k<<<(N_NODES*512/4+255)/256, 256, 0, stream>>>(h1, h1b, N_NODES*512);
    logits_k<<<N_NODES, 256, 0, stream>>>(h1, as1f, ad1f, als1, ald1, HEADS, HID);
    aggregate_k<HEADS, HID, true, false>
        <<<N_NODES, (HEADS*HID)/4, 0, stream>>>(h1b, als1, ald1, offs, ssrc, b1f, pwf, h1p, flag);

    // ---- layer 2 ----
    dim3 g2(256/128, (N_NODES+127)/128);
    gemm_k<<<g2, 256, 0, stream>>>(h1p, W2f, h2, N_NODES, OUT_CH, 512);
    f2bf_k<<<(N_NODES*256/4+255)/256, 256, 0, stream>>>(h2, h2b, N_NODES*256);
    logits_k<<<N_NODES, 64, 0, stream>>>(h2, as2f, ad2f, als2v, ald2v, 1, OUT_CH);
    aggregate_k<1, OUT_CH, false, true>
        <<<N_NODES, OUT_CH/4, 0, stream>>>(h2b, als2v, ald2v, offs, ssrc, b2f, nullptr, d_out, flag);
}

// Round 4
// 467.780 us; speedup vs baseline: 1.5946x; 1.4282x over previous
//
#include <hip/hip_runtime.h>
#include <hip/hip_bf16.h>
#include <float.h>

#define N_NODES 30000
#define IN_CH   256
#define HID     128
#define HEADS   4
#define OUT_CH  256
#define N_EDGES 480000
#define TOT_E   (N_EDGES + N_NODES)

typedef unsigned short u16;   // bf16 bits
typedef __attribute__((ext_vector_type(8))) unsigned short u16x8;
typedef __attribute__((ext_vector_type(8))) short          s16x8;  // MFMA A/B frag (8 bf16)
typedef __attribute__((ext_vector_type(4))) float          f32x4;  // MFMA C/D frag

__device__ inline float bf2f(u16 u) {
    union { unsigned int i; float f; } v; v.i = ((unsigned int)u) << 16; return v.f;
}
__device__ inline u16 f2bf(float f) {
    union { float f; unsigned int i; } u; u.f = f;
    unsigned int r = u.i + 0x7FFF + ((u.i >> 16) & 1);
    return (u16)(r >> 16);
}

__device__ inline void load4(const float* p, float* o) {
    float4 v = *(const float4*)p; o[0]=v.x; o[1]=v.y; o[2]=v.z; o[3]=v.w;
}
__device__ inline void store4f(float* p, float a, float b, float c, float d) {
    *(float4*)p = make_float4(a,b,c,d);
}
__device__ inline void store4b(u16* p, float a, float b, float c, float d) {
    ushort4 o; o.x=f2bf(a); o.y=f2bf(b); o.z=f2bf(c); o.w=f2bf(d);
    *(ushort4*)p = o;
}

// ---------- dtype detection: bf16 exponent field vs fp32 mantissa bits -----
__global__ void detect_k(const unsigned int* __restrict__ w, int* __restrict__ flag) {
    __shared__ int votes;
    if (threadIdx.x == 0) votes = 0;
    __syncthreads();
    int v = 0;
    for (int i = threadIdx.x; i < 2048; i += 256) {
        unsigned int e = (w[i] >> 7) & 0xFFu;
        if (e >= 100u && e <= 140u) v++;
    }
    atomicAdd(&votes, v);
    __syncthreads();
    if (threadIdx.x == 0) *flag = (votes > 1024) ? 1 : 0;
}

// materialize an input as fp32 regardless of its on-disk dtype
__global__ void convert_k(const void* __restrict__ in, float* __restrict__ out,
                          int n, const int* __restrict__ flag) {
    int i = blockIdx.x * blockDim.x + threadIdx.x;
    if (i >= n) return;
    if (*flag) out[i] = bf2f(((const u16*)in)[i]);
    else       out[i] = ((const float*)in)[i];
}

// materialize an input as bf16 regardless of its on-disk dtype
__global__ void convert_bf_k(const void* __restrict__ in, u16* __restrict__ out,
                             int n, const int* __restrict__ flag) {
    int i = blockIdx.x * blockDim.x + threadIdx.x;
    if (i >= n) return;
    if (*flag) out[i] = ((const u16*)in)[i];
    else       out[i] = f2bf(((const float*)in)[i]);
}

// materialize a [rows][cols] input as TRANSPOSED bf16 [cols][rows]
__global__ void convert_tr_k(const void* __restrict__ in, u16* __restrict__ out,
                             int rows, int cols, const int* __restrict__ flag) {
    int i = blockIdx.x * blockDim.x + threadIdx.x;
    if (i >= rows * cols) return;
    int r = i / cols, c = i - r * cols;
    u16 v = (*flag) ? ((const u16*)in)[i] : f2bf(((const float*)in)[i]);
    out[(size_t)c * rows + r] = v;
}

// ---------------- MFMA GEMM: C[M,N] = A[M,K] @ Bt[N,K]^T, bf16 in, fp32 acc
// A row-major bf16 [M][K]; Bt row-major bf16 [N][K] (pre-transposed weights).
// Writes C fp32 and Cb bf16 (fused mirror for the gather stage).
// 128x128 tile, BK=32, 4 waves in 2x2, each wave 64x64 = 4x4 MFMA frags.
// mfma_f32_16x16x32_bf16 layouts (learn_hip m89-verified):
//   A: row=lane&15, k=8*(lane>>4)+i   B: col=lane&15, k=8*(lane>>4)+i
//   C/D: col=lane&15, row=(lane>>4)*4+reg
__global__ __launch_bounds__(256) void gemm_bf_k(const u16* __restrict__ A,
                                                 const u16* __restrict__ Bt,
                                                 float* __restrict__ C,
                                                 u16* __restrict__ Cb,
                                                 int M, int N, int K)
{
    // stride 40 u16 (80 B) rows: fragment b128 reads land 2-way on banks (free)
    __shared__ __align__(16) u16 As[128][40];
    __shared__ __align__(16) u16 Bs[128][40];

    const int tid  = threadIdx.x;
    const int wid  = tid >> 6;
    const int lane = tid & 63;
    const int wr   = wid >> 1;          // wave row 0..1
    const int wc   = wid & 1;           // wave col 0..1
    const int lr   = lane & 15;         // frag row/col
    const int lg   = lane >> 4;         // k-group 0..3
    const int row0 = blockIdx.y * 128;
    const int col0 = blockIdx.x * 128;

    // staging: thread t covers row t>>1, 16 cols starting at (t&1)*16
    const int st_r = tid >> 1;
    const int st_c = (tid & 1) << 4;

    f32x4 acc[4][4];
#pragma unroll
    for (int i = 0; i < 4; ++i)
#pragma unroll
        for (int j = 0; j < 4; ++j)
            acc[i][j] = (f32x4){0.f, 0.f, 0.f, 0.f};

    for (int k0 = 0; k0 < K; k0 += 32) {
        __syncthreads();
        {
            u16x8 a0 = {}, a1 = {};
            int ar = row0 + st_r;
            if (ar < M) {
                const u16* ap = A + (size_t)ar * K + k0 + st_c;
                a0 = *(const u16x8*)ap;
                a1 = *(const u16x8*)(ap + 8);
            }
            *(u16x8*)&As[st_r][st_c]     = a0;
            *(u16x8*)&As[st_r][st_c + 8] = a1;
            // N is a multiple of 128 -> no guard needed on B
            const u16* bp = Bt + (size_t)(col0 + st_r) * K + k0 + st_c;
            *(u16x8*)&Bs[st_r][st_c]     = *(const u16x8*)bp;
            *(u16x8*)&Bs[st_r][st_c + 8] = *(const u16x8*)(bp + 8);
        }
        __syncthreads();

        s16x8 af[4], bf[4];
#pragma unroll
        for (int mf = 0; mf < 4; ++mf)
            af[mf] = *(const s16x8*)&As[wr*64 + mf*16 + lr][lg*8];
#pragma unroll
        for (int nf = 0; nf < 4; ++nf)
            bf[nf] = *(const s16x8*)&Bs[wc*64 + nf*16 + lr][lg*8];
#pragma unroll
        for (int mf = 0; mf < 4; ++mf)
#pragma unroll
            for (int nf = 0; nf < 4; ++nf)
                acc[mf][nf] = __builtin_amdgcn_mfma_f32_16x16x32_bf16(
                    af[mf], bf[nf], acc[mf][nf], 0, 0, 0);
    }

    // epilogue: dual store fp32 + bf16 mirror
#pragma unroll
    for (int mf = 0; mf < 4; ++mf) {
#pragma unroll
        for (int r = 0; r < 4; ++r) {
            int rr = row0 + wr*64 + mf*16 + lg*4 + r;
            if (rr >= M) continue;
            size_t base = (size_t)rr * N + col0 + wc*64 + lr;
#pragma unroll
            for (int nf = 0; nf < 4; ++nf) {
                float v = acc[mf][nf][r];
                C [base + nf*16] = v;
                Cb[base + nf*16] = f2bf(v);
            }
        }
    }
}

// ------------- per-node attention logits ------------------------------------
__global__ void logits_k(const float* __restrict__ h,
                         const float* __restrict__ a_s,
                         const float* __restrict__ a_d,
                         float* __restrict__ als, float* __restrict__ ald,
                         int H, int C)
{
    int n = blockIdx.x;
    int head = threadIdx.x >> 6;
    int lane = threadIdx.x & 63;
    const float* row = h + (size_t)n * H * C + head * C;
    float ss = 0.f, sd = 0.f;
    for (int c = lane; c < C; c += 64) {
        float v = row[c];
        ss += v * a_s[head*C + c];
        sd += v * a_d[head*C + c];
    }
    for (int o = 32; o > 0; o >>= 1) { ss += __shfl_down(ss,o); sd += __shfl_down(sd,o); }
    if (lane == 0) { als[(size_t)n*H + head] = ss; ald[(size_t)n*H + head] = sd; }
}

// ---------------- CSR build -------------------------------------------------
__global__ void zero_k(int* p, int n) {
    int i = blockIdx.x*blockDim.x + threadIdx.x; if (i < n) p[i] = 0;
}
__global__ void count_k(const int* __restrict__ ei, int* __restrict__ cnt) {
    int i = blockIdx.x*blockDim.x + threadIdx.x;
    if (i >= TOT_E) return;
    int d = (i < N_EDGES) ? ei[N_EDGES + i] : (i - N_EDGES);
    atomicAdd(&cnt[d], 1);
}
__global__ __launch_bounds__(1024) void scan_k(const int* __restrict__ cnt,
                                               int* __restrict__ offs,
                                               int* __restrict__ cursor)
{
    __shared__ int sm[1024];
    __shared__ int carry_s;
    if (threadIdx.x == 0) carry_s = 0;
    __syncthreads();
    for (int base = 0; base < N_NODES; base += 1024) {
        int i = base + threadIdx.x;
        int v = (i < N_NODES) ? cnt[i] : 0;
        sm[threadIdx.x] = v;
        __syncthreads();
        for (int off = 1; off < 1024; off <<= 1) {
            int t = (threadIdx.x >= off) ? sm[threadIdx.x - off] : 0;
            __syncthreads();
            sm[threadIdx.x] += t;
            __syncthreads();
        }
        int c = carry_s;
        if (i < N_NODES) {
            offs[i+1]  = c + sm[threadIdx.x];
            cursor[i]  = c + sm[threadIdx.x] - v;
        }
        __syncthreads();
        if (threadIdx.x == 1023) carry_s = c + sm[1023];
        __syncthreads();
    }
    if (threadIdx.x == 0) offs[0] = 0;
}
__global__ void scatter_k(const int* __restrict__ ei, int* __restrict__ cursor,
                          int* __restrict__ ssrc)
{
    int i = blockIdx.x*blockDim.x + threadIdx.x;
    if (i >= TOT_E) return;
    int s, d;
    if (i < N_EDGES) { s = ei[i]; d = ei[N_EDGES + i]; }
    else             { s = i - N_EDGES; d = s; }
    int pos = atomicAdd(&cursor[d], 1);
    ssrc[pos] = s;
}

// ---------------- per-dst softmax + weighted aggregation --------------------
// one block per dst node; T = H*C/4 threads, each owns 4 contiguous channels.
// Gathers from a bf16 mirror (traffic-bound per round-2/3 counters).
// OUTMODE: 0 = fp32, 1 = bf16 always (feeds gemm2's A operand), 2 = runtime flag
template<int H, int C, bool PRELU, int OUTMODE>
__global__ void aggregate_k(const u16* __restrict__ hb,
                            const float* __restrict__ als,
                            const float* __restrict__ ald,
                            const int* __restrict__ offs,
                            const int* __restrict__ ssrc,
                            const float* __restrict__ bias,
                            const float* __restrict__ prelu_w,
                            void* __restrict__ outv,
                            const int* __restrict__ flag)
{
    constexpr int CT = H * C;
    constexpr int T  = CT / 4;
    constexpr int NW = T / 64;            // waves per block
    int n   = blockIdx.x;
    int tid = threadIdx.x;
    int beg = offs[n], end = offs[n+1];

    __shared__ float s_ald[H], s_m[H], s_inv[H];
    __shared__ float red[H][NW];
    __shared__ int   sh_s[T];
    __shared__ float sh_w[H][T];

    if (tid < H) s_ald[tid] = ald[(size_t)n*H + tid];
    __syncthreads();

    // sweep 1: per-head max of leaky logits (wave shuffle reduce)
    float lmax[H];
#pragma unroll
    for (int hh = 0; hh < H; ++hh) lmax[hh] = -FLT_MAX;
    for (int e = beg + tid; e < end; e += T) {
        int s = ssrc[e];
#pragma unroll
        for (int hh = 0; hh < H; ++hh) {
            float l = als[(size_t)s*H + hh] + s_ald[hh];
            l = (l >= 0.f) ? l : 0.2f*l;
            lmax[hh] = fmaxf(lmax[hh], l);
        }
    }
#pragma unroll
    for (int hh = 0; hh < H; ++hh) {
        float v = lmax[hh];
#pragma unroll
        for (int o = 32; o > 0; o >>= 1) v = fmaxf(v, __shfl_xor(v, o));
        if ((tid & 63) == 0) red[hh][tid >> 6] = v;
    }
    __syncthreads();
    if (tid < H) {
        float v = red[tid][0];
#pragma unroll
        for (int w2 = 1; w2 < NW; ++w2) v = fmaxf(v, red[tid][w2]);
        s_m[tid] = v;
    }
    __syncthreads();

    // sweep 2: per-head sum of exp(l - m)
    float lsum[H];
#pragma unroll
    for (int hh = 0; hh < H; ++hh) lsum[hh] = 0.f;
    for (int e = beg + tid; e < end; e += T) {
        int s = ssrc[e];
#pragma unroll
        for (int hh = 0; hh < H; ++hh) {
            float l = als[(size_t)s*H + hh] + s_ald[hh];
            l = (l >= 0.f) ? l : 0.2f*l;
            lsum[hh] += __expf(l - s_m[hh]);
        }
    }
#pragma unroll
    for (int hh = 0; hh < H; ++hh) {
        float v = lsum[hh];
#pragma unroll
        for (int o = 32; o > 0; o >>= 1) v += __shfl_xor(v, o);
        if ((tid & 63) == 0) red[hh][tid >> 6] = v;
    }
    __syncthreads();
    if (tid < H) {
        float v = 0.f;
#pragma unroll
        for (int w2 = 0; w2 < NW; ++w2) v += red[tid][w2];
        s_inv[tid] = 1.0f / v;
    }
    __syncthreads();

    // pass 3: chunk-staged weighted gather from the bf16 mirror
    const int hh = (4*tid) / C;
    float ax = 0.f, ay = 0.f, az = 0.f, aw = 0.f;
    for (int chunk = beg; chunk < end; chunk += T) {
        int e = chunk + tid;
        if (e < end) {
            int s = ssrc[e];
            sh_s[tid] = s;
#pragma unroll
            for (int h2 = 0; h2 < H; ++h2) {
                float l = als[(size_t)s*H + h2] + s_ald[h2];
                l = (l >= 0.f) ? l : 0.2f*l;
                sh_w[h2][tid] = __expf(l - s_m[h2]) * s_inv[h2];
            }
        }
        __syncthreads();
        int cnt = min(T, end - chunk);
        int j = 0;
        for (; j + 4 <= cnt; j += 4) {
            int s0 = sh_s[j+0], s1 = sh_s[j+1], s2 = sh_s[j+2], s3 = sh_s[j+3];
            float w0 = sh_w[hh][j+0], w1 = sh_w[hh][j+1];
            float w2 = sh_w[hh][j+2], w3 = sh_w[hh][j+3];
            ushort4 v0 = *(const ushort4*)(hb + (size_t)s0*CT + 4*tid);
            ushort4 v1 = *(const ushort4*)(hb + (size_t)s1*CT + 4*tid);
            ushort4 v2 = *(const ushort4*)(hb + (size_t)s2*CT + 4*tid);
            ushort4 v3 = *(const ushort4*)(hb + (size_t)s3*CT + 4*tid);
            ax += w0*bf2f(v0.x); ay += w0*bf2f(v0.y); az += w0*bf2f(v0.z); aw += w0*bf2f(v0.w);
            ax += w1*bf2f(v1.x); ay += w1*bf2f(v1.y); az += w1*bf2f(v1.z); aw += w1*bf2f(v1.w);
            ax += w2*bf2f(v2.x); ay += w2*bf2f(v2.y); az += w2*bf2f(v2.z); aw += w2*bf2f(v2.w);
            ax += w3*bf2f(v3.x); ay += w3*bf2f(v3.y); az += w3*bf2f(v3.z); aw += w3*bf2f(v3.w);
        }
        for (; j < cnt; ++j) {
            int s0 = sh_s[j];
            float w0 = sh_w[hh][j];
            ushort4 v0 = *(const ushort4*)(hb + (size_t)s0*CT + 4*tid);
            ax += w0*bf2f(v0.x); ay += w0*bf2f(v0.y); az += w0*bf2f(v0.z); aw += w0*bf2f(v0.w);
        }
        __syncthreads();
    }

    float bb[4];
    load4(bias + 4*tid, bb);
    ax += bb[0]; ay += bb[1]; az += bb[2]; aw += bb[3];
    if (PRELU) {
        float pw = *prelu_w;
        ax = ax >= 0.f ? ax : pw*ax;
        ay = ay >= 0.f ? ay : pw*ay;
        az = az >= 0.f ? az : pw*az;
        aw = aw >= 0.f ? aw : pw*aw;
    }
    size_t ofs = (size_t)n*CT + 4*tid;
    if (OUTMODE == 2) {
        if (*flag) store4b((u16*)outv + ofs, ax, ay, az, aw);
        else       store4f((float*)outv + ofs, ax, ay, az, aw);
    } else if (OUTMODE == 1) {
        store4b((u16*)outv + ofs, ax, ay, az, aw);
    } else {
        store4f((float*)outv + ofs, ax, ay, az, aw);
    }
}

// ---------------------------------------------------------------------------
extern "C" void kernel_launch(void* const* d_in, const int* in_sizes, int n_in,
                              void* d_out, int out_size, void* d_ws, size_t ws_size,
                              hipStream_t stream)
{
    const void* x   = d_in[0];
    const int*  ei  = (const int*)d_in[1];
    const void* W1  = d_in[2];
    const void* as1 = d_in[3];
    const void* ad1 = d_in[4];
    const void* b1  = d_in[5];
    const void* pw  = d_in[6];
    const void* W2  = d_in[7];
    const void* as2 = d_in[8];
    const void* ad2 = d_in[9];
    const void* b2  = d_in[10];

    float* ws = (float*)d_ws;
    int*   flag = (int*)ws;                               // 16-slot pad
    float* as1f = ws + 16;                                // 512
    float* ad1f = as1f + HEADS*HID;                       // 512
    float* b1f  = ad1f + HEADS*HID;                       // 512
    float* as2f = b1f  + HEADS*HID;                       // 256
    float* ad2f = as2f + OUT_CH;                          // 256
    float* b2f  = ad2f + OUT_CH;                          // 256
    float* pwf  = b2f  + OUT_CH;                          // 4 (pad to 8)
    u16*   W1t  = (u16*)(pwf + 8);                        // 131072 u16 = 65536 slots
    u16*   W2t  = W1t + IN_CH*HEADS*HID;                  // 131072 u16 = 65536 slots
    float* als1 = (float*)(W2t + HEADS*HID*OUT_CH);       // 120,000
    float* ald1 = als1 + (size_t)N_NODES*4;               // 120,000
    float* als2v = ald1 + (size_t)N_NODES*4;              // 30,000
    float* ald2v = als2v + N_NODES;                       // 30,000
    int*   cnt    = (int*)(ald2v + N_NODES);              // 30,000
    int*   offs   = cnt + N_NODES;                        // 30,001
    int*   cursor = offs + (N_NODES+1);                   // 30,000
    int*   ssrc   = cursor + N_NODES;                     // 510,000 (+pad)
    u16*   xb     = (u16*)(ssrc + 510004);                // 7,680,000 u16 = 3.84M slots
    float* h1     = (float*)(xb + (size_t)N_NODES*IN_CH); // 15,360,000 slots
    u16*   h1b    = (u16*)(h1 + (size_t)N_NODES*512);     // 15,360,000 u16 = 7.68M slots
    // aliases (lifetime-checked):
    u16*   h1pb = (u16*)h1;            // aggregate1 out; h1 dead after logits1
    float* h2   = h1 + (size_t)N_NODES*256;  // gemm2 out; disjoint from h1pb bytes
    u16*   h2b  = h1b;                 // gemm2 bf16 mirror; h1b dead after aggregate1

    // dtype detect + materialize inputs
    detect_k<<<1, 256, 0, stream>>>((const unsigned int*)x, flag);
    convert_bf_k<<<(N_NODES*IN_CH+255)/256, 256, 0, stream>>>(x, xb, N_NODES*IN_CH, flag);
    convert_tr_k<<<(IN_CH*HEADS*HID+255)/256, 256, 0, stream>>>(W1, W1t, IN_CH, HEADS*HID, flag);
    convert_tr_k<<<(HEADS*HID*OUT_CH+255)/256, 256, 0, stream>>>(W2, W2t, HEADS*HID, OUT_CH, flag);
    convert_k<<<2, 256, 0, stream>>>(as1, as1f, HEADS*HID, flag);
    convert_k<<<2, 256, 0, stream>>>(ad1, ad1f, HEADS*HID, flag);
    convert_k<<<2, 256, 0, stream>>>(b1,  b1f,  HEADS*HID, flag);
    convert_k<<<1, 256, 0, stream>>>(as2, as2f, OUT_CH, flag);
    convert_k<<<1, 256, 0, stream>>>(ad2, ad2f, OUT_CH, flag);
    convert_k<<<1, 256, 0, stream>>>(b2,  b2f,  OUT_CH, flag);
    convert_k<<<1, 64,  0, stream>>>(pw,  pwf,  1, flag);

    // CSR build
    zero_k   <<<(N_NODES+255)/256, 256, 0, stream>>>(cnt, N_NODES);
    count_k  <<<(TOT_E+255)/256,   256, 0, stream>>>(ei, cnt);
    scan_k   <<<1, 1024, 0, stream>>>(cnt, offs, cursor);
    scatter_k<<<(TOT_E+255)/256,   256, 0, stream>>>(ei, cursor, ssrc);

    // ---- layer 1 ----
    dim3 g1(512/128, (N_NODES+127)/128);
    gemm_bf_k<<<g1, 256, 0, stream>>>(xb, W1t, h1, h1b, N_NODES, 512, IN_CH);
    logits_k<<<N_NODES, 256, 0, stream>>>(h1, as1f, ad1f, als1, ald1, HEADS, HID);
    aggregate_k<HEADS, HID, true, 1>
        <<<N_NODES, (HEADS*HID)/4, 0, stream>>>(h1b, als1, ald1, offs, ssrc, b1f, pwf, h1pb, flag);

    // ---- layer 2 ----
    dim3 g2(256/128, (N_NODES+127)/128);
    gemm_bf_k<<<g2, 256, 0, stream>>>(h1pb, W2t, h2, h2b, N_NODES, OUT_CH, HEADS*HID);
    logits_k<<<N_NODES, 64, 0, stream>>>(h2, as2f, ad2f, als2v, ald2v, 1, OUT_CH);
    aggregate_k<1, OUT_CH, false, 2>
        <<<N_NODES, OUT_CH/4, 0, stream>>>(h2b, als2v, ald2v, offs, ssrc, b2f, nullptr, d_out, flag);
}

// Round 5
// 375.711 us; speedup vs baseline: 1.9853x; 1.2451x over previous
//
#include <hip/hip_runtime.h>
#include <hip/hip_bf16.h>
#include <float.h>

#define N_NODES 30000
#define IN_CH   256
#define HID     128
#define HEADS   4
#define OUT_CH  256
#define N_EDGES 480000
#define TOT_E   (N_EDGES + N_NODES)

typedef unsigned short u16;   // bf16 bits
typedef __attribute__((ext_vector_type(8))) unsigned short u16x8;
typedef __attribute__((ext_vector_type(8))) short          s16x8;  // MFMA A/B frag (8 bf16)
typedef __attribute__((ext_vector_type(4))) float          f32x4;  // MFMA C/D frag

__device__ inline float bf2f(u16 u) {
    union { unsigned int i; float f; } v; v.i = ((unsigned int)u) << 16; return v.f;
}
__device__ inline u16 f2bf(float f) {
    union { float f; unsigned int i; } u; u.f = f;
    unsigned int r = u.i + 0x7FFF + ((u.i >> 16) & 1);
    return (u16)(r >> 16);
}

__device__ inline void load4(const float* p, float* o) {
    float4 v = *(const float4*)p; o[0]=v.x; o[1]=v.y; o[2]=v.z; o[3]=v.w;
}
__device__ inline void store4f(float* p, float a, float b, float c, float d) {
    *(float4*)p = make_float4(a,b,c,d);
}
__device__ inline void store4b(u16* p, float a, float b, float c, float d) {
    ushort4 o; o.x=f2bf(a); o.y=f2bf(b); o.z=f2bf(c); o.w=f2bf(d);
    *(ushort4*)p = o;
}

// ---------- dtype detection: bf16 exponent field vs fp32 mantissa bits -----
__global__ void detect_k(const unsigned int* __restrict__ w, int* __restrict__ flag) {
    __shared__ int votes;
    if (threadIdx.x == 0) votes = 0;
    __syncthreads();
    int v = 0;
    for (int i = threadIdx.x; i < 2048; i += 256) {
        unsigned int e = (w[i] >> 7) & 0xFFu;
        if (e >= 100u && e <= 140u) v++;
    }
    atomicAdd(&votes, v);
    __syncthreads();
    if (threadIdx.x == 0) *flag = (votes > 1024) ? 1 : 0;
}

// materialize an input as bf16 regardless of its on-disk dtype
__global__ void convert_bf_k(const void* __restrict__ in, u16* __restrict__ out,
                             int n, const int* __restrict__ flag) {
    int i = blockIdx.x * blockDim.x + threadIdx.x;
    if (i >= n) return;
    if (*flag) out[i] = ((const u16*)in)[i];
    else       out[i] = f2bf(((const float*)in)[i]);
}

// materialize a [rows][cols] input as TRANSPOSED bf16 [cols][rows]
__global__ void convert_tr_k(const void* __restrict__ in, u16* __restrict__ out,
                             int rows, int cols, const int* __restrict__ flag) {
    int i = blockIdx.x * blockDim.x + threadIdx.x;
    if (i >= rows * cols) return;
    int r = i / cols, c = i - r * cols;
    u16 v = (*flag) ? ((const u16*)in)[i] : f2bf(((const float*)in)[i]);
    out[(size_t)c * rows + r] = v;
}

// all 7 small vectors in one launch (2305 elements total)
__global__ void convert_small_k(const void* __restrict__ as1, const void* __restrict__ ad1,
                                const void* __restrict__ b1,  const void* __restrict__ as2,
                                const void* __restrict__ ad2, const void* __restrict__ b2,
                                const void* __restrict__ pw,
                                float* __restrict__ as1f, float* __restrict__ ad1f,
                                float* __restrict__ b1f,  float* __restrict__ as2f,
                                float* __restrict__ ad2f, float* __restrict__ b2f,
                                float* __restrict__ pwf,
                                const int* __restrict__ flag)
{
    int i = blockIdx.x * blockDim.x + threadIdx.x;
    int f = *flag;
#define CV(in, k) (f ? bf2f(((const u16*)(in))[k]) : ((const float*)(in))[k])
    if      (i < 512)  as1f[i]        = CV(as1, i);
    else if (i < 1024) ad1f[i - 512]  = CV(ad1, i - 512);
    else if (i < 1536) b1f [i - 1024] = CV(b1,  i - 1024);
    else if (i < 1792) as2f[i - 1536] = CV(as2, i - 1536);
    else if (i < 2048) ad2f[i - 1792] = CV(ad2, i - 1792);
    else if (i < 2304) b2f [i - 2048] = CV(b2,  i - 2048);
    else if (i == 2304) pwf[0]        = CV(pw, 0);
#undef CV
}

// ---------------- MFMA GEMM + fused logits epilogue ------------------------
// C[M,N] = A[M,K] @ Bt[N,K]^T, bf16 in, fp32 acc. Writes ONLY the bf16
// mirror Cb (gather + next-GEMM operand); the attention logits
// als[r,h] = sum_j C[r,j]*a_s[j] (and ald) are computed from the fp32 acc
// registers (exact) via 16-lane shfl reduce + one atomicAdd per row.
// 128x128 tile, BK=32, 4 waves in 2x2, each wave 64x64 = 4x4 MFMA frags.
// mfma_f32_16x16x32_bf16 layouts (learn_hip m89-verified):
//   A: row=lane&15, k=8*(lane>>4)+i   B: col=lane&15, k=8*(lane>>4)+i
//   C/D: col=lane&15, row=(lane>>4)*4+reg
__global__ __launch_bounds__(256) void gemm_bf_k(const u16* __restrict__ A,
                                                 const u16* __restrict__ Bt,
                                                 u16* __restrict__ Cb,
                                                 const float* __restrict__ a_s,
                                                 const float* __restrict__ a_d,
                                                 float* __restrict__ als,
                                                 float* __restrict__ ald,
                                                 int M, int N, int K,
                                                 int H, int hshift)
{
    // stride 40 u16 (80 B) rows: fragment b128 reads land 2-way on banks (free)
    __shared__ __align__(16) u16 As[128][40];
    __shared__ __align__(16) u16 Bs[128][40];

    const int tid  = threadIdx.x;
    const int wid  = tid >> 6;
    const int lane = tid & 63;
    const int wr   = wid >> 1;          // wave row 0..1
    const int wc   = wid & 1;           // wave col 0..1
    const int lr   = lane & 15;         // frag row/col
    const int lg   = lane >> 4;         // k-group 0..3
    const int row0 = blockIdx.y * 128;
    const int col0 = blockIdx.x * 128;

    // staging: thread t covers row t>>1, 16 cols starting at (t&1)*16
    const int st_r = tid >> 1;
    const int st_c = (tid & 1) << 4;

    f32x4 acc[4][4];
#pragma unroll
    for (int i = 0; i < 4; ++i)
#pragma unroll
        for (int j = 0; j < 4; ++j)
            acc[i][j] = (f32x4){0.f, 0.f, 0.f, 0.f};

    for (int k0 = 0; k0 < K; k0 += 32) {
        __syncthreads();
        {
            u16x8 a0 = {}, a1 = {};
            int ar = row0 + st_r;
            if (ar < M) {
                const u16* ap = A + (size_t)ar * K + k0 + st_c;
                a0 = *(const u16x8*)ap;
                a1 = *(const u16x8*)(ap + 8);
            }
            *(u16x8*)&As[st_r][st_c]     = a0;
            *(u16x8*)&As[st_r][st_c + 8] = a1;
            // N is a multiple of 128 -> no guard needed on B
            const u16* bp = Bt + (size_t)(col0 + st_r) * K + k0 + st_c;
            *(u16x8*)&Bs[st_r][st_c]     = *(const u16x8*)bp;
            *(u16x8*)&Bs[st_r][st_c + 8] = *(const u16x8*)(bp + 8);
        }
        __syncthreads();

        s16x8 af[4], bf[4];
#pragma unroll
        for (int mf = 0; mf < 4; ++mf)
            af[mf] = *(const s16x8*)&As[wr*64 + mf*16 + lr][lg*8];
#pragma unroll
        for (int nf = 0; nf < 4; ++nf)
            bf[nf] = *(const s16x8*)&Bs[wc*64 + nf*16 + lr][lg*8];
#pragma unroll
        for (int mf = 0; mf < 4; ++mf)
#pragma unroll
            for (int nf = 0; nf < 4; ++nf)
                acc[mf][nf] = __builtin_amdgcn_mfma_f32_16x16x32_bf16(
                    af[mf], bf[nf], acc[mf][nf], 0, 0, 0);
    }

    // epilogue: bf16 store + fused logits partials
    const int head = (col0 + wc*64) >> hshift;
    float asj[4], adj[4];
#pragma unroll
    for (int nf = 0; nf < 4; ++nf) {
        int j = col0 + wc*64 + nf*16 + lr;
        asj[nf] = a_s[j];
        adj[nf] = a_d[j];
    }
#pragma unroll
    for (int mf = 0; mf < 4; ++mf) {
#pragma unroll
        for (int r = 0; r < 4; ++r) {
            int rr = row0 + wr*64 + mf*16 + lg*4 + r;
            float ss = 0.f, sd = 0.f;
#pragma unroll
            for (int nf = 0; nf < 4; ++nf) {
                float v = acc[mf][nf][r];
                ss += v * asj[nf];
                sd += v * adj[nf];
            }
            // reduce the 16 lanes (lr=0..15) holding this row's 16 cols
#pragma unroll
            for (int m2 = 1; m2 < 16; m2 <<= 1) {
                ss += __shfl_xor(ss, m2);
                sd += __shfl_xor(sd, m2);
            }
            if (rr < M) {
                if (lr == 0) {
                    atomicAdd(&als[(size_t)rr * H + head], ss);
                    atomicAdd(&ald[(size_t)rr * H + head], sd);
                }
                size_t base = (size_t)rr * N + col0 + wc*64 + lr;
#pragma unroll
                for (int nf = 0; nf < 4; ++nf)
                    Cb[base + nf*16] = f2bf(acc[mf][nf][r]);
            }
        }
    }
}

// ---------------- CSR build -------------------------------------------------
__global__ void zero_k(int* p, int n) {
    int i = blockIdx.x*blockDim.x + threadIdx.x; if (i < n) p[i] = 0;
}
__global__ void count_k(const int* __restrict__ ei, int* __restrict__ cnt) {
    int i = blockIdx.x*blockDim.x + threadIdx.x;
    if (i >= TOT_E) return;
    int d = (i < N_EDGES) ? ei[N_EDGES + i] : (i - N_EDGES);
    atomicAdd(&cnt[d], 1);
}
// 3-phase parallel scan (replaces the single-block serial scan)
__global__ __launch_bounds__(1024) void scan1_k(const int* __restrict__ cnt,
                                                int* __restrict__ offs,
                                                int* __restrict__ btot)
{
    __shared__ int sm[1024];
    int tid = threadIdx.x;
    int i = blockIdx.x * 1024 + tid;
    int v = (i < N_NODES) ? cnt[i] : 0;
    sm[tid] = v;
    __syncthreads();
    for (int off = 1; off < 1024; off <<= 1) {
        int t = (tid >= off) ? sm[tid - off] : 0;
        __syncthreads();
        sm[tid] += t;
        __syncthreads();
    }
    if (i < N_NODES) offs[i + 1] = sm[tid];   // local inclusive scan
    if (tid == 1023) btot[blockIdx.x] = sm[1023];
}
__global__ void scan2_k(const int* __restrict__ btot, int* __restrict__ bpref, int nb)
{
    int lane = threadIdx.x;
    int orig = (lane < nb) ? btot[lane] : 0;
    int v = orig;
    for (int off = 1; off < 64; off <<= 1) {
        int t = __shfl_up(v, off);
        if (lane >= off) v += t;
    }
    if (lane < nb) bpref[lane] = v - orig;    // exclusive prefix
}
__global__ __launch_bounds__(1024) void scan3_k(const int* __restrict__ cnt,
                                                int* __restrict__ offs,
                                                int* __restrict__ cursor,
                                                const int* __restrict__ bpref)
{
    int i = blockIdx.x * 1024 + threadIdx.x;
    if (i < N_NODES) {
        int inc = offs[i + 1] + bpref[blockIdx.x];
        offs[i + 1] = inc;
        cursor[i]   = inc - cnt[i];
    }
    if (i == 0) offs[0] = 0;
}
__global__ void scatter_k(const int* __restrict__ ei, int* __restrict__ cursor,
                          int* __restrict__ ssrc)
{
    int i = blockIdx.x*blockDim.x + threadIdx.x;
    if (i >= TOT_E) return;
    int s, d;
    if (i < N_EDGES) { s = ei[i]; d = ei[N_EDGES + i]; }
    else             { s = i - N_EDGES; d = s; }
    int pos = atomicAdd(&cursor[d], 1);
    ssrc[pos] = s;
}

// ---------------- per-dst softmax + weighted aggregation --------------------
// one block per dst node; T = H*C/4 threads, each owns 4 contiguous channels.
// Gathers from a bf16 mirror (traffic-bound per round-2/3/4 counters).
// OUTMODE: 0 = fp32, 1 = bf16 always (feeds gemm2's A operand), 2 = runtime flag
template<int H, int C, bool PRELU, int OUTMODE>
__global__ void aggregate_k(const u16* __restrict__ hb,
                            const float* __restrict__ als,
                            const float* __restrict__ ald,
                            const int* __restrict__ offs,
                            const int* __restrict__ ssrc,
                            const float* __restrict__ bias,
                            const float* __restrict__ prelu_w,
                            void* __restrict__ outv,
                            const int* __restrict__ flag)
{
    constexpr int CT = H * C;
    constexpr int T  = CT / 4;
    constexpr int NW = T / 64;            // waves per block
    int n   = blockIdx.x;
    int tid = threadIdx.x;
    int beg = offs[n], end = offs[n+1];

    __shared__ float s_ald[H], s_m[H], s_inv[H];
    __shared__ float red[H][NW];
    __shared__ int   sh_s[T];
    __shared__ float sh_w[H][T];

    if (tid < H) s_ald[tid] = ald[(size_t)n*H + tid];
    __syncthreads();

    // sweep 1: per-head max of leaky logits (wave shuffle reduce)
    float lmax[H];
#pragma unroll
    for (int hh = 0; hh < H; ++hh) lmax[hh] = -FLT_MAX;
    for (int e = beg + tid; e < end; e += T) {
        int s = ssrc[e];
#pragma unroll
        for (int hh = 0; hh < H; ++hh) {
            float l = als[(size_t)s*H + hh] + s_ald[hh];
            l = (l >= 0.f) ? l : 0.2f*l;
            lmax[hh] = fmaxf(lmax[hh], l);
        }
    }
#pragma unroll
    for (int hh = 0; hh < H; ++hh) {
        float v = lmax[hh];
#pragma unroll
        for (int o = 32; o > 0; o >>= 1) v = fmaxf(v, __shfl_xor(v, o));
        if ((tid & 63) == 0) red[hh][tid >> 6] = v;
    }
    __syncthreads();
    if (tid < H) {
        float v = red[tid][0];
#pragma unroll
        for (int w2 = 1; w2 < NW; ++w2) v = fmaxf(v, red[tid][w2]);
        s_m[tid] = v;
    }
    __syncthreads();

    // sweep 2: per-head sum of exp(l - m)
    float lsum[H];
#pragma unroll
    for (int hh = 0; hh < H; ++hh) lsum[hh] = 0.f;
    for (int e = beg + tid; e < end; e += T) {
        int s = ssrc[e];
#pragma unroll
        for (int hh = 0; hh < H; ++hh) {
            float l = als[(size_t)s*H + hh] + s_ald[hh];
            l = (l >= 0.f) ? l : 0.2f*l;
            lsum[hh] += __expf(l - s_m[hh]);
        }
    }
#pragma unroll
    for (int hh = 0; hh < H; ++hh) {
        float v = lsum[hh];
#pragma unroll
        for (int o = 32; o > 0; o >>= 1) v += __shfl_xor(v, o);
        if ((tid & 63) == 0) red[hh][tid >> 6] = v;
    }
    __syncthreads();
    if (tid < H) {
        float v = 0.f;
#pragma unroll
        for (int w2 = 0; w2 < NW; ++w2) v += red[tid][w2];
        s_inv[tid] = 1.0f / v;
    }
    __syncthreads();

    // pass 3: chunk-staged weighted gather from the bf16 mirror
    const int hh = (4*tid) / C;
    float ax = 0.f, ay = 0.f, az = 0.f, aw = 0.f;
    for (int chunk = beg; chunk < end; chunk += T) {
        int e = chunk + tid;
        if (e < end) {
            int s = ssrc[e];
            sh_s[tid] = s;
#pragma unroll
            for (int h2 = 0; h2 < H; ++h2) {
                float l = als[(size_t)s*H + h2] + s_ald[h2];
                l = (l >= 0.f) ? l : 0.2f*l;
                sh_w[h2][tid] = __expf(l - s_m[h2]) * s_inv[h2];
            }
        }
        __syncthreads();
        int cnt = min(T, end - chunk);
        int j = 0;
        for (; j + 4 <= cnt; j += 4) {
            int s0 = sh_s[j+0], s1 = sh_s[j+1], s2 = sh_s[j+2], s3 = sh_s[j+3];
            float w0 = sh_w[hh][j+0], w1 = sh_w[hh][j+1];
            float w2 = sh_w[hh][j+2], w3 = sh_w[hh][j+3];
            ushort4 v0 = *(const ushort4*)(hb + (size_t)s0*CT + 4*tid);
            ushort4 v1 = *(const ushort4*)(hb + (size_t)s1*CT + 4*tid);
            ushort4 v2 = *(const ushort4*)(hb + (size_t)s2*CT + 4*tid);
            ushort4 v3 = *(const ushort4*)(hb + (size_t)s3*CT + 4*tid);
            ax += w0*bf2f(v0.x); ay += w0*bf2f(v0.y); az += w0*bf2f(v0.z); aw += w0*bf2f(v0.w);
            ax += w1*bf2f(v1.x); ay += w1*bf2f(v1.y); az += w1*bf2f(v1.z); aw += w1*bf2f(v1.w);
            ax += w2*bf2f(v2.x); ay += w2*bf2f(v2.y); az += w2*bf2f(v2.z); aw += w2*bf2f(v2.w);
            ax += w3*bf2f(v3.x); ay += w3*bf2f(v3.y); az += w3*bf2f(v3.z); aw += w3*bf2f(v3.w);
        }
        for (; j < cnt; ++j) {
            int s0 = sh_s[j];
            float w0 = sh_w[hh][j];
            ushort4 v0 = *(const ushort4*)(hb + (size_t)s0*CT + 4*tid);
            ax += w0*bf2f(v0.x); ay += w0*bf2f(v0.y); az += w0*bf2f(v0.z); aw += w0*bf2f(v0.w);
        }
        __syncthreads();
    }

    float bb[4];
    load4(bias + 4*tid, bb);
    ax += bb[0]; ay += bb[1]; az += bb[2]; aw += bb[3];
    if (PRELU) {
        float pw = *prelu_w;
        ax = ax >= 0.f ? ax : pw*ax;
        ay = ay >= 0.f ? ay : pw*ay;
        az = az >= 0.f ? az : pw*az;
        aw = aw >= 0.f ? aw : pw*aw;
    }
    size_t ofs = (size_t)n*CT + 4*tid;
    if (OUTMODE == 2) {
        if (*flag) store4b((u16*)outv + ofs, ax, ay, az, aw);
        else       store4f((float*)outv + ofs, ax, ay, az, aw);
    } else if (OUTMODE == 1) {
        store4b((u16*)outv + ofs, ax, ay, az, aw);
    } else {
        store4f((float*)outv + ofs, ax, ay, az, aw);
    }
}

// ---------------------------------------------------------------------------
extern "C" void kernel_launch(void* const* d_in, const int* in_sizes, int n_in,
                              void* d_out, int out_size, void* d_ws, size_t ws_size,
                              hipStream_t stream)
{
    const void* x   = d_in[0];
    const int*  ei  = (const int*)d_in[1];
    const void* W1  = d_in[2];
    const void* as1 = d_in[3];
    const void* ad1 = d_in[4];
    const void* b1  = d_in[5];
    const void* pw  = d_in[6];
    const void* W2  = d_in[7];
    const void* as2 = d_in[8];
    const void* ad2 = d_in[9];
    const void* b2  = d_in[10];

    float* ws = (float*)d_ws;
    int*   flag = (int*)ws;                               // 16 slots
    float* as1f = ws + 16;                                // 512
    float* ad1f = as1f + 512;                             // 512
    float* b1f  = ad1f + 512;                             // 512
    float* as2f = b1f  + 512;                             // 256
    float* ad2f = as2f + 256;                             // 256
    float* b2f  = ad2f + 256;                             // 256
    float* pwf  = b2f  + 256;                             // 16
    u16*   W1t  = (u16*)(pwf + 16);                       // 131072 u16 = 65536 slots
    u16*   W2t  = W1t + IN_CH*HEADS*HID;                  // 131072 u16 = 65536 slots
    // contiguous zero region: als1..ald2v (fp32, atomically accumulated) + cnt
    float* als1 = (float*)(W2t + HEADS*HID*OUT_CH);       // 120000
    float* ald1 = als1 + (size_t)N_NODES*HEADS;           // 120000
    float* als2v = ald1 + (size_t)N_NODES*HEADS;          // 30000
    float* ald2v = als2v + N_NODES;                       // 30000
    int*   cnt    = (int*)(ald2v + N_NODES);              // 30000
    int*   offs   = cnt + N_NODES;                        // 30004 (pad)
    int*   cursor = offs + 30004;                         // 30000
    int*   btot   = cursor + N_NODES;                     // 32
    int*   bpref  = btot + 32;                            // 32 (+ pad 4)
    int*   ssrc   = bpref + 36;                           // 510000 (+pad 4)
    u16*   xb     = (u16*)(ssrc + 510004);                // 30000*256 u16
    u16*   h1b    = xb  + (size_t)N_NODES*IN_CH;          // 30000*512 u16
    u16*   h1pb   = h1b + (size_t)N_NODES*512;            // 30000*512 u16
    u16*   h2b    = h1b;   // alias: h1b dead after aggregate1

    const int NB = (N_NODES + 1023) / 1024;   // 30 scan blocks

    // dtype detect + materialize inputs
    detect_k<<<1, 256, 0, stream>>>((const unsigned int*)x, flag);
    convert_bf_k<<<(N_NODES*IN_CH+255)/256, 256, 0, stream>>>(x, xb, N_NODES*IN_CH, flag);
    convert_tr_k<<<(IN_CH*HEADS*HID+255)/256, 256, 0, stream>>>(W1, W1t, IN_CH, HEADS*HID, flag);
    convert_tr_k<<<(HEADS*HID*OUT_CH+255)/256, 256, 0, stream>>>(W2, W2t, HEADS*HID, OUT_CH, flag);
    convert_small_k<<<10, 256, 0, stream>>>(as1, ad1, b1, as2, ad2, b2, pw,
                                            as1f, ad1f, b1f, as2f, ad2f, b2f, pwf, flag);

    // zero logits accumulators + CSR counters in one pass (contiguous, 330000 ints)
    zero_k<<<(330000+255)/256, 256, 0, stream>>>((int*)als1, 330000);

    // CSR build (parallel scan)
    count_k  <<<(TOT_E+255)/256, 256, 0, stream>>>(ei, cnt);
    scan1_k  <<<NB, 1024, 0, stream>>>(cnt, offs, btot);
    scan2_k  <<<1, 64, 0, stream>>>(btot, bpref, NB);
    scan3_k  <<<NB, 1024, 0, stream>>>(cnt, offs, cursor, bpref);
    scatter_k<<<(TOT_E+255)/256, 256, 0, stream>>>(ei, cursor, ssrc);

    // ---- layer 1 ----  (gemm fuses logits; writes bf16 h1b only)
    dim3 g1(512/128, (N_NODES+127)/128);
    gemm_bf_k<<<g1, 256, 0, stream>>>(xb, W1t, h1b, as1f, ad1f, als1, ald1,
                                      N_NODES, 512, IN_CH, HEADS, 7);
    aggregate_k<HEADS, HID, true, 1>
        <<<N_NODES, (HEADS*HID)/4, 0, stream>>>(h1b, als1, ald1, offs, ssrc, b1f, pwf, h1pb, flag);

    // ---- layer 2 ----
    dim3 g2(256/128, (N_NODES+127)/128);
    gemm_bf_k<<<g2, 256, 0, stream>>>(h1pb, W2t, h2b, as2f, ad2f, als2v, ald2v,
                                      N_NODES, OUT_CH, HEADS*HID, 1, 8);
    aggregate_k<1, OUT_CH, false, 2>
        <<<N_NODES, OUT_CH/4, 0, stream>>>(h2b, als2v, ald2v, offs, ssrc, b2f, nullptr, d_out, flag);
}